// Round 3
// baseline (304.116 us; speedup 1.0000x reference)
//
#include <hip/hip_runtime.h>

// ---------------------------------------------------------------------------
// PositionEncoder: per token (B*T = 262144), output 272 f32:
//   x[0:6] | emb[idx1] (128) | x[6:10] | emb[idx2] (128) | x[10:16]
// idx from matching (x[4],x[5]) / (x[8],x[9]) vs 26 nodes,
// close iff |p - node| <= 0.01 + 1e-5*|node| per dim; idx = first match + 1.
//
// History:
//  R2 (LDS out-tile, plain st)  ~126 us kernel
//  R4 (LDS out-tile, nt st)     ~125 us
//  R5/R6 (direct, nt st)        ~120 us   <- occupancy/barriers were NOT it
//  All three pin effective store BW at ~2.4 TB/s while the harness fill
//  writes the SAME buffer at 6.43 TB/s with plain dwordx4. Suspect:
//  __builtin_nontemporal_store lowers to sc0+sc1+nt (system-scope, bypasses
//  L2 line aggregation) => ~2.5x write BW loss on 16B stores.
// R7 (this): plain stores + wave-per-token register templates.
//  idx==0 for ~99.7% of tokens (x~N(0,1) vs tol 0.01) => both emb rows are
//  emb[0]; each lane's output vec4 is a kernel-lifetime constant except 6
//  x-dependent slots. Per token: 4 broadcast ds_read_b128 (x row) + ~16
//  cndmask + 2 plain stores. Rare idx!=0 tokens: wave-uniform slow path via
//  the R6-verified half-mapping over semb.
// ---------------------------------------------------------------------------

#define TOK 64          // tokens per block
#define THREADS 256
#define TPW (TOK / 4)   // tokens per wave = 16

typedef float vfloat4 __attribute__((ext_vector_type(4)));  // native vector

constexpr float kNX[26] = {
    0.5454545454545454f, 0.6022727272727273f, 0.5454545454545454f,
    0.6022727272727273f, 0.4772727272727273f, 0.42045454545454547f,
    0.42045454545454547f, 0.4772727272727273f, 0.32954545454545453f,
    0.42045454545454547f, 0.4772727272727273f, 0.4772727272727273f,
    0.42045454545454547f, 0.32954545454545453f, 0.5727272727272728f,
    0.7613636363636364f, 0.8181818181818182f, 0.8181818181818182f,
    0.7613636363636364f, 0.7909090909090909f, 0.9431818181818182f,
    1.0f, 1.0f, 0.9431818181818182f, 0.9727272727272728f, 0.9727272727272728f};
constexpr float kNY[26] = {
    0.76f, 0.76f, 0.86f, 0.86f, 0.76f, 0.76f, 0.86f, 0.86f, 0.808f,
    0.48f, 0.48f, 0.38f, 0.38f, 0.428f, 0.62f, 0.76f, 0.76f, 0.86f,
    0.86f, 0.62f, 0.76f, 0.76f, 0.86f, 0.86f, 0.62f, 1.0f};

__device__ __forceinline__ int point_index(float px, float py) {
#pragma clang fp contract(off)
    int idx = 0;
    // Reverse iterate + overwrite => lowest-index match wins (== argmax of
    // the boolean "close" vector, matching the reference exactly).
#pragma unroll
    for (int n = 25; n >= 0; --n) {
        float tx = 0.01f + 1.0e-5f * kNX[n];   // compile-time folded
        float ty = 0.01f + 1.0e-5f * kNY[n];
        bool c = (fabsf(px - kNX[n]) <= tx) && (fabsf(py - kNY[n]) <= ty);
        if (c) idx = n + 1;
    }
    return idx;
}

// General (slow-path) half: float2 index h of token t's 136-float2 output row.
//   h<3: x[2h..]  h<67: e1[2h-6..]  h<69: x[2h-128..]
//   h<133: e2[2h-138..]  else x[2h-256..]        (verified in R6, absmax 0)
__device__ __forceinline__ float2 ghalf(const float2* xs2, const float2* se2,
                                        int h, int tb, int i1, int i2) {
    return (h < 3)   ? xs2[tb + h]
         : (h < 67)  ? se2[i1 * 64 + (h - 3)]
         : (h < 69)  ? xs2[tb + (h - 64)]
         : (h < 133) ? se2[i2 * 64 + (h - 69)]
         :             xs2[tb + (h - 128)];
}

__device__ __forceinline__ vfloat4 gvec4(const float2* xs2, const float2* se2,
                                         int j, int tb, int i1, int i2) {
    float2 a = ghalf(xs2, se2, 2 * j, tb, i1, i2);
    float2 b = ghalf(xs2, se2, 2 * j + 1, tb, i1, i2);
    vfloat4 v; v.x = a.x; v.y = a.y; v.z = b.x; v.w = b.y;
    return v;
}

__global__ __launch_bounds__(THREADS) void pos_enc_kernel(
    const float* __restrict__ x, const float* __restrict__ emb,
    float* __restrict__ out, int n_tokens) {
    __shared__ float xs[TOK * 16];      // 4 KB   staged x tile
    __shared__ float semb[27 * 128];    // 13.5 KB emb rows 0..26 (reachable set)
    __shared__ int   sidx[2 * TOK];     // 0.5 KB node indices

    const int tid  = threadIdx.x;
    const int lane = tid & 63;
    const int wave = tid >> 6;
    const int tok0 = blockIdx.x * TOK;
    const int ntok = min(TOK, n_tokens - tok0);

    // ---- stage emb rows 0..26: 864 float4, coalesced, L2-hot after block 0
    for (int i = tid; i < 27 * 32; i += THREADS)
        ((vfloat4*)semb)[i] = ((const vfloat4*)emb)[i];

    // ---- stage x tile (1 float4/thread) + node indices from the staging reg
    if (tid < ntok * 4) {
        vfloat4 v = ((const vfloat4*)x)[(long long)tok0 * 4 + tid];
        ((vfloat4*)xs)[tid] = v;
        int q = tid & 3, t = tid >> 2;
        int pi = point_index(v.x, v.y);   // one pass; only q==1/2 use it
        if (q == 1) sidx[t]       = pi;
        if (q == 2) sidx[TOK + t] = pi;
    }
    __syncthreads();   // the only barrier

    // ---- per-lane register templates built from emb row 0 (idx==0 case) ----
    const float2* e0  = (const float2*)semb;      // emb row 0 as float2
    const float2* xs2 = (const float2*)xs;
    const float2* se2 = (const float2*)semb;

    float2 Ta, Tb;          // store1 template, j = lane   (halves 2j, 2j+1)
    {
        int h0 = 2 * lane, h1 = h0 + 1;
        Ta = (h0 >= 3 && h0 < 67) ? e0[h0 - 3]
           : (h0 >= 69 && h0 < 133) ? e0[h0 - 69] : float2{0.f, 0.f};
        Tb = (h1 >= 3 && h1 < 67) ? e0[h1 - 3]
           : (h1 >= 69 && h1 < 133) ? e0[h1 - 69] : float2{0.f, 0.f};
    }
    float2 Ua, Ub;          // store2 template, j = 64 + lane (lanes 0..3 used)
    {
        int h0 = 128 + 2 * lane, h1 = h0 + 1;
        Ua = (h0 < 133) ? e0[h0 - 69] : float2{0.f, 0.f};
        Ub = (h1 < 133) ? e0[h1 - 69] : float2{0.f, 0.f};
    }
    // lane-class masks (loop-invariant; compiler hoists the v_cmps)
    const bool j0 = (lane == 0), j1 = (lane == 1);
    const bool j33 = (lane == 33), j34 = (lane == 34);
    const bool l2m = (lane == 2), l3m = (lane == 3);

    // ---- which of this wave's tokens need the general path? (rare) ----
    const int wt0 = wave * TPW;
    unsigned long long spec = __ballot(
        lane < TPW && (wt0 + lane) < ntok &&
        ((sidx[wt0 + lane] | sidx[TOK + wt0 + lane]) != 0));

    // ---- token loop: 2 plain dwordx4 stores per token ----
    vfloat4* outp = (vfloat4*)out + ((long long)(tok0 + wt0)) * 68;
#pragma unroll 2
    for (int it = 0; it < TPW; ++it, outp += 68) {
        int t = wt0 + it;
        if (t >= ntok) break;
        // broadcast-read token's x row (uniform address -> conflict-free)
        vfloat4 xA = ((const vfloat4*)xs)[t * 4 + 0];   // x0..3
        vfloat4 xB = ((const vfloat4*)xs)[t * 4 + 1];   // x4..7
        vfloat4 xC = ((const vfloat4*)xs)[t * 4 + 2];   // x8..11
        vfloat4 xD = ((const vfloat4*)xs)[t * 4 + 3];   // x12..15

        vfloat4 v;  // j = lane
        v.x = j0 ? xA.x : j1 ? xB.x : j34 ? xC.x : Ta.x;
        v.y = j0 ? xA.y : j1 ? xB.y : j34 ? xC.y : Ta.y;
        v.z = j0 ? xA.z : j33 ? xB.z : Tb.x;
        v.w = j0 ? xA.w : j33 ? xB.w : Tb.y;

        vfloat4 u;  // j = 64 + lane (lanes 0..3)
        u.x = l3m ? xD.x : Ua.x;
        u.y = l3m ? xD.y : Ua.y;
        u.z = l2m ? xC.z : l3m ? xD.z : Ub.x;
        u.w = l2m ? xC.w : l3m ? xD.w : Ub.y;

        if (spec & (1ull << it)) {      // wave-uniform, ~0.2% of tokens
            int i1 = sidx[t], i2 = sidx[TOK + t], tb = t * 8;
            v = gvec4(xs2, se2, lane, tb, i1, i2);
            if (lane < 4) u = gvec4(xs2, se2, 64 + lane, tb, i1, i2);
        }

        outp[lane] = v;                         // plain store: L2 write-combine
        if (lane < 4) outp[64 + lane] = u;
    }
}

extern "C" void kernel_launch(void* const* d_in, const int* in_sizes, int n_in,
                              void* d_out, int out_size, void* d_ws, size_t ws_size,
                              hipStream_t stream) {
    const float* x   = (const float*)d_in[0];   // [B, T, 16] f32
    const float* emb = (const float*)d_in[1];   // [100, 128] f32
    float* out = (float*)d_out;                 // [B, T, 272] f32

    int n_tokens = in_sizes[0] / 16;            // 262144
    int nblocks  = (n_tokens + TOK - 1) / TOK;  // 4096

    pos_enc_kernel<<<nblocks, THREADS, 0, stream>>>(x, emb, out, n_tokens);
}

// Round 4
// 303.224 us; speedup vs baseline: 1.0029x; 1.0029x over previous
//
#include <hip/hip_runtime.h>

// ---------------------------------------------------------------------------
// PositionEncoder: per token (B*T = 262144), output 272 f32:
//   x[0:6] | emb[idx1] (128) | x[6:10] | emb[idx2] (128) | x[10:16]
// idx from matching (x[4],x[5]) / (x[8],x[9]) vs 26 nodes,
// close iff |p - node| <= 0.01 + 1e-5*|node| per dim; idx = first match + 1.
//
// History (kernel-resid = dur_us - ~180us harness poison fill):
//  R2 tile+plain   ~126   (confounded: 4 blk/CU, 3 barriers, LDS roundtrip)
//  R4 tile+nt      ~125
//  R6 direct+nt    ~120   flat fill-like geometry, nt stores
//  R7 template+plain ~117 2 stores/token but 1088B rows -> partial lines
//  Compute side is exonerated: R7 cut VALU/LDS/store-count hugely, moved 3us.
// R8 (this): R6 verbatim, nt -> PLAIN stores. The harness fill proves plain
//  full-line dwordx4 streams elide RFO (1.14GB written, FETCH=14.5KB,
//  6.4TB/s). R6's geometry is fill-identical (every wave-store 1024B
//  contiguous, 128B aligned, block region contiguous); only its nt flavor
//  (sc0 sc1 nt, bypasses L2 aggregation) differs. Clean A/B on store flavor.
// ---------------------------------------------------------------------------

#define TOK 64          // tokens per block
#define THREADS 256

typedef float vfloat4 __attribute__((ext_vector_type(4)));  // native vector

constexpr float kNX[26] = {
    0.5454545454545454f, 0.6022727272727273f, 0.5454545454545454f,
    0.6022727272727273f, 0.4772727272727273f, 0.42045454545454547f,
    0.42045454545454547f, 0.4772727272727273f, 0.32954545454545453f,
    0.42045454545454547f, 0.4772727272727273f, 0.4772727272727273f,
    0.42045454545454547f, 0.32954545454545453f, 0.5727272727272728f,
    0.7613636363636364f, 0.8181818181818182f, 0.8181818181818182f,
    0.7613636363636364f, 0.7909090909090909f, 0.9431818181818182f,
    1.0f, 1.0f, 0.9431818181818182f, 0.9727272727272728f, 0.9727272727272728f};
constexpr float kNY[26] = {
    0.76f, 0.76f, 0.86f, 0.86f, 0.76f, 0.76f, 0.86f, 0.86f, 0.808f,
    0.48f, 0.48f, 0.38f, 0.38f, 0.428f, 0.62f, 0.76f, 0.76f, 0.86f,
    0.86f, 0.62f, 0.76f, 0.76f, 0.86f, 0.86f, 0.62f, 1.0f};

__device__ __forceinline__ int point_index(float px, float py) {
#pragma clang fp contract(off)
    int idx = 0;
    // Reverse iterate + overwrite => lowest-index match wins (== argmax of
    // the boolean "close" vector, matching the reference exactly).
#pragma unroll
    for (int n = 25; n >= 0; --n) {
        float tx = 0.01f + 1.0e-5f * kNX[n];   // compile-time folded
        float ty = 0.01f + 1.0e-5f * kNY[n];
        bool c = (fabsf(px - kNX[n]) <= tx) && (fabsf(py - kNY[n]) <= ty);
        if (c) idx = n + 1;
    }
    return idx;
}

__global__ __launch_bounds__(THREADS) void pos_enc_kernel(
    const float* __restrict__ x, const float* __restrict__ emb,
    float* __restrict__ out, int n_tokens) {
    __shared__ float xs[TOK * 16];      // 4 KB   staged x tile
    __shared__ float semb[27 * 128];    // 13.5 KB emb rows 0..26 (reachable set)
    __shared__ int   sidx[2 * TOK];     // 0.5 KB node indices

    const int tid  = threadIdx.x;
    const int tok0 = blockIdx.x * TOK;
    const int ntok = min(TOK, n_tokens - tok0);

    // ---- stage emb rows 0..26: 864 float4, coalesced, L2-hot after block 0
    for (int i = tid; i < 27 * 32; i += THREADS)
        ((vfloat4*)semb)[i] = ((const vfloat4*)emb)[i];

    // ---- stage x tile (1 float4/thread) + node indices from the staging reg
    if (tid < ntok * 4) {
        vfloat4 v = ((const vfloat4*)x)[(long long)tok0 * 4 + tid];
        ((vfloat4*)xs)[tid] = v;
        int q = tid & 3, t = tid >> 2;
        if (q == 1) sidx[t]       = point_index(v.x, v.y);
        if (q == 2) sidx[TOK + t] = point_index(v.x, v.y);
    }
    __syncthreads();   // the only barrier

    // ---- direct store: flat l -> (t = l/68, j = l%68) float4 of the row.
    // All row-segment boundaries (floats 6,134,138,266) are even, so each
    // 16B output vec4 is two float2 halves, each from exactly one source.
    // Half h (float2 units, 0..135):
    //   h<3: x[2h..]  h<67: e1[2h-6..]  h<69: x[2h-128..]
    //   h<133: e2[2h-138..]  else x[2h-256..]
    const float2* xs2 = (const float2*)xs;
    const float2* se2 = (const float2*)semb;
    const long long out4 = (long long)tok0 * 68;

    // exact for l < ~1M: floor(l*61681 / 2^22) == floor(l/68)
#define BODY(lv)                                                           \
    {                                                                      \
        const int l_ = (lv);                                               \
        int t  = (int)(((unsigned)l_ * 61681u) >> 22);                     \
        int j  = l_ - t * 68;                                              \
        int i1 = sidx[t];                                                  \
        int i2 = sidx[TOK + t];                                            \
        int tb = t * 8;                                                    \
        int h0 = 2 * j;                                                    \
        const float2* p0 = (h0 < 3)   ? xs2 + tb + h0                      \
                         : (h0 < 67)  ? se2 + i1 * 64 + (h0 - 3)           \
                         : (h0 < 69)  ? xs2 + tb + (h0 - 64)               \
                         : (h0 < 133) ? se2 + i2 * 64 + (h0 - 69)          \
                         :              xs2 + tb + (h0 - 128);             \
        int h1 = h0 + 1;                                                   \
        const float2* p1 = (h1 < 3)   ? xs2 + tb + h1                      \
                         : (h1 < 67)  ? se2 + i1 * 64 + (h1 - 3)           \
                         : (h1 < 69)  ? xs2 + tb + (h1 - 64)               \
                         : (h1 < 133) ? se2 + i2 * 64 + (h1 - 69)          \
                         :              xs2 + tb + (h1 - 128);             \
        float2 a = *p0, b = *p1;                                           \
        vfloat4 v; v.x = a.x; v.y = a.y; v.z = b.x; v.w = b.y;             \
        ((vfloat4*)out)[out4 + l_] = v;   /* PLAIN store (R8 change) */    \
    }

    if (ntok == TOK) {
        // full block: every thread does exactly 17 vec4 (64*68/256)
#pragma unroll 4
        for (int k = 0; k < 17; ++k) BODY(tid + (k << 8));
    } else {
        const int nvec = ntok * 68;
        for (int l = tid; l < nvec; l += THREADS) BODY(l);
    }
#undef BODY
}

extern "C" void kernel_launch(void* const* d_in, const int* in_sizes, int n_in,
                              void* d_out, int out_size, void* d_ws, size_t ws_size,
                              hipStream_t stream) {
    const float* x   = (const float*)d_in[0];   // [B, T, 16] f32
    const float* emb = (const float*)d_in[1];   // [100, 128] f32
    float* out = (float*)d_out;                 // [B, T, 272] f32

    int n_tokens = in_sizes[0] / 16;            // 262144
    int nblocks  = (n_tokens + TOK - 1) / TOK;  // 4096

    pos_enc_kernel<<<nblocks, THREADS, 0, stream>>>(x, emb, out, n_tokens);
}